// Round 2
// baseline (539.007 us; speedup 1.0000x reference)
//
#include <hip/hip_runtime.h>
#include <hip/hip_bf16.h>

#define B_ 2
#define N_ 2048
#define C_ 1024
#define H_ 16
#define D_ 64
#define F_ 4096
#define M_ 4096  // B_*N_

typedef __attribute__((ext_vector_type(8))) short bf16x8;
typedef __attribute__((ext_vector_type(4))) float f32x4;

__device__ inline unsigned short f2bf(float f) {
  unsigned int u = __float_as_uint(f);
  u = (u + 0x7FFFu + ((u >> 16) & 1u)) >> 16;
  return (unsigned short)u;
}
__device__ inline float bf2f(unsigned short s) {
  return __uint_as_float(((unsigned int)s) << 16);
}

// ---------------- all-weights fp32 -> bf16 in one launch ---------------------
__global__ __launch_bounds__(256)
void cvt_all(const float4* __restrict__ s0, const float4* __restrict__ s1,
             const float4* __restrict__ s2, const float4* __restrict__ s3,
             const float4* __restrict__ s4, const float4* __restrict__ s5,
             ushort4* __restrict__ d0, ushort4* __restrict__ d1,
             ushort4* __restrict__ d2, ushort4* __restrict__ d3,
             ushort4* __restrict__ d4, ushort4* __restrict__ d5) {
  int b = blockIdx.x;
  const float4* s; ushort4* d; int i;
  if      (b < 1024) { s = s0; d = d0; i = b * 256 + threadIdx.x; }
  else if (b < 2048) { s = s1; d = d1; i = (b - 1024) * 256 + threadIdx.x; }
  else if (b < 3072) { s = s2; d = d2; i = (b - 2048) * 256 + threadIdx.x; }
  else if (b < 4096) { s = s3; d = d3; i = (b - 3072) * 256 + threadIdx.x; }
  else if (b < 8192) { s = s4; d = d4; i = (b - 4096) * 256 + threadIdx.x; }
  else               { s = s5; d = d5; i = (b - 8192) * 256 + threadIdx.x; }
  float4 f = s[i];
  ushort4 o;
  o.x = f2bf(f.x); o.y = f2bf(f.y); o.z = f2bf(f.z); o.w = f2bf(f.w);
  d[i] = o;
}

// ---------------- LayerNorm: fp32 in -> bf16 out, one block per row (C=1024) --
__global__ __launch_bounds__(256)
void ln_kernel(const float* __restrict__ x, const float* __restrict__ g,
               const float* __restrict__ b, unsigned short* __restrict__ out) {
  __shared__ float red[8];
  const int row = blockIdx.x;
  const int t = threadIdx.x;
  const float4 xv = *(const float4*)(x + row * 1024 + t * 4);
  float s  = xv.x + xv.y + xv.z + xv.w;
  float sq = xv.x * xv.x + xv.y * xv.y + xv.z * xv.z + xv.w * xv.w;
  #pragma unroll
  for (int off = 32; off >= 1; off >>= 1) {
    s  += __shfl_down(s, off);
    sq += __shfl_down(sq, off);
  }
  const int lane = t & 63, wave = t >> 6;
  if (lane == 0) { red[wave * 2] = s; red[wave * 2 + 1] = sq; }
  __syncthreads();
  float ts = red[0] + red[2] + red[4] + red[6];
  float tq = red[1] + red[3] + red[5] + red[7];
  float mean = ts * (1.0f / 1024.0f);
  float var  = tq * (1.0f / 1024.0f) - mean * mean;
  float rstd = rsqrtf(var + 1e-6f);
  float xs[4] = {xv.x, xv.y, xv.z, xv.w};
  #pragma unroll
  for (int i = 0; i < 4; i++) {
    int c = t * 4 + i;
    float y = (xs[i] - mean) * rstd * g[c] + b[c];
    out[row * 1024 + c] = f2bf(y);
  }
}

// ---------------- GEMM: out[m,n] = sum_k A[m,k]*Bw[n,k] (+epilogue) ----------
// m97 structure: unpadded 128x64 LDS tiles + global_load_lds width=16.
// MODE 0: -> bf16 out (no bias)                 [QKV]
// MODE 1: +bias +resid -> fp32 out              [O-proj -> x1]
// MODE 2: +bias, exact GELU -> bf16 out         [MLP1]
// MODE 3: +bias +resid -> fp32 out              [MLP2 -> d_out]
template<int MODE>
__global__ __launch_bounds__(256)
void gemm_bt(const unsigned short* __restrict__ A,
             const unsigned short* __restrict__ Bw,
             int K, int Nout,
             const float* __restrict__ bias,
             const float* __restrict__ resid,
             unsigned short* __restrict__ out_bf,
             float* __restrict__ out_f32) {
  __shared__ unsigned short sA[128 * 64];   // unpadded: global_load_lds needs contiguity
  __shared__ unsigned short sB[128 * 64];
  const int t = threadIdx.x;
  const int wave = t >> 6, lane = t & 63;
  const int quad = lane >> 4, l16 = lane & 15;
  const int wm = (wave & 1) * 64, wn = (wave >> 1) * 64;
  const int m0 = blockIdx.y * 128, n0 = blockIdx.x * 128;

  f32x4 acc[4][4];
  #pragma unroll
  for (int i = 0; i < 4; i++)
    #pragma unroll
    for (int j = 0; j < 4; j++) acc[i][j] = (f32x4){0.f, 0.f, 0.f, 0.f};

  // per-lane global src: row = t>>3 (+32i), 16B chunk = (t&7)*8 shorts
  const unsigned short* gA = A  + (m0 + (t >> 3)) * K + (t & 7) * 8;
  const unsigned short* gB = Bw + (n0 + (t >> 3)) * K + (t & 7) * 8;
  unsigned short* lA = &sA[(wave * 8) * 64];   // wave-uniform base; HW adds lane*16B
  unsigned short* lB = &sB[(wave * 8) * 64];

  for (int k0 = 0; k0 < K; k0 += 64) {
    #pragma unroll
    for (int i = 0; i < 4; i++) {
      __builtin_amdgcn_global_load_lds((const unsigned int*)(gA + (32 * i) * K + k0),
                                       (unsigned int*)(lA + 32 * i * 64), 16, 0, 0);
      __builtin_amdgcn_global_load_lds((const unsigned int*)(gB + (32 * i) * K + k0),
                                       (unsigned int*)(lB + 32 * i * 64), 16, 0, 0);
    }
    __syncthreads();
    #pragma unroll
    for (int kk = 0; kk < 2; kk++) {
      bf16x8 af[4], bfr[4];
      #pragma unroll
      for (int i = 0; i < 4; i++)
        af[i] = *(const bf16x8*)(&sA[(wm + i * 16 + l16) * 64 + kk * 32 + quad * 8]);
      #pragma unroll
      for (int j = 0; j < 4; j++)
        bfr[j] = *(const bf16x8*)(&sB[(wn + j * 16 + l16) * 64 + kk * 32 + quad * 8]);
      #pragma unroll
      for (int i = 0; i < 4; i++)
        #pragma unroll
        for (int j = 0; j < 4; j++)
          acc[i][j] = __builtin_amdgcn_mfma_f32_16x16x32_bf16(af[i], bfr[j], acc[i][j], 0, 0, 0);
    }
    __syncthreads();
  }

  // epilogue: C/D layout col=lane&15, row=quad*4+reg  [m89/m91 verified]
  #pragma unroll
  for (int i = 0; i < 4; i++) {
    #pragma unroll
    for (int j = 0; j < 4; j++) {
      int col = n0 + wn + j * 16 + l16;
      #pragma unroll
      for (int r = 0; r < 4; r++) {
        int row = m0 + wm + i * 16 + quad * 4 + r;
        float v = acc[i][j][r];
        if (MODE == 0) {
          out_bf[row * Nout + col] = f2bf(v);
        } else if (MODE == 1) {
          out_f32[row * Nout + col] = v + bias[col] + resid[row * Nout + col];
        } else if (MODE == 2) {
          v += bias[col];
          float gl = 0.5f * v * (1.0f + erff(v * 0.70710678118654752f));
          out_bf[row * Nout + col] = f2bf(gl);
        } else {
          out_f32[row * Nout + col] = v + bias[col] + resid[row * Nout + col];
        }
      }
    }
  }
}

// ---------------- RoPE + bias + head split: (M,3C) qkv -> (B*H,N,D) q,k,v ----
// q is pre-scaled by D^-0.5 = 0.125 so flash_attn skips the multiply.
__global__ __launch_bounds__(256)
void rope_split(const unsigned short* __restrict__ qkv,
                const float* __restrict__ bq, const float* __restrict__ bk,
                const float* __restrict__ bv,
                const float* __restrict__ rc, const float* __restrict__ rs,
                unsigned short* __restrict__ qo, unsigned short* __restrict__ ko,
                unsigned short* __restrict__ vo) {
  int idx = blockIdx.x * 256 + threadIdx.x;  // 0..M_*C_-1
  int m = idx >> 10, c = idx & 1023;
  int h = c >> 6, d = c & 63;
  int b = m >> 11, n = m & 2047;
  int base = m * 3072;
  float qv = bf2f(qkv[base + c])        + bq[c];
  float kv = bf2f(qkv[base + 1024 + c]) + bk[c];
  float vv = bf2f(qkv[base + 2048 + c]) + bv[c];
  int c2 = (d < 32) ? c + 32 : c - 32;
  float qp = bf2f(qkv[base + c2])        + bq[c2];
  float kp = bf2f(qkv[base + 1024 + c2]) + bk[c2];
  float rqv = (d < 32) ? -qp : qp;   // rotate_half
  float rkv = (d < 32) ? -kp : kp;
  float cs = rc[n * 64 + d], sn = rs[n * 64 + d];
  int oi = ((b * 16 + h) * 2048 + n) * 64 + d;
  qo[oi] = f2bf((qv * cs + rqv * sn) * 0.125f);
  ko[oi] = f2bf(kv * cs + rkv * sn);
  vo[oi] = f2bf(vv);
}

// ---------------- Flash attention: per (b,h), 64 q-rows per block -------------
// K tile staged via global_load_lds (unpadded). V tile stored transposed with an
// XOR block swizzle: element (kv,d) at sVt[d*64 + (kv ^ 8*((d>>3)&7))] ->
// scalar writes land 2 lanes/bank (free), reads stay 16B-aligned b128.
__global__ __launch_bounds__(256)
void flash_attn(const unsigned short* __restrict__ q,
                const unsigned short* __restrict__ k,
                const unsigned short* __restrict__ v,
                unsigned short* __restrict__ o) {
  __shared__ unsigned short sK[64 * 64];
  __shared__ unsigned short sVt[64 * 64];
  __shared__ unsigned short sP[4][16][72];
  const int t = threadIdx.x;
  const int wave = t >> 6, lane = t & 63;
  const int quad = lane >> 4, l16 = lane & 15;
  const int bh = blockIdx.y;
  const int qb = blockIdx.x;
  const int base = bh * (N_ * D_);

  bf16x8 qa[2];
  {
    int qrow = qb * 64 + wave * 16 + l16;
    #pragma unroll
    for (int kk = 0; kk < 2; kk++)
      qa[kk] = *(const bf16x8*)(q + base + qrow * D_ + kk * 32 + quad * 8);
  }
  float m_i[4], l_i[4];
  f32x4 o_acc[4];
  #pragma unroll
  for (int r = 0; r < 4; r++) { m_i[r] = -1e30f; l_i[r] = 0.f; }
  #pragma unroll
  for (int dt = 0; dt < 4; dt++) o_acc[dt] = (f32x4){0.f, 0.f, 0.f, 0.f};

  const unsigned short* gK = k + base + (t >> 3) * 64 + (t & 7) * 8;
  unsigned short* lK = &sK[(wave * 8) * 64];

  for (int kt = 0; kt < N_ / 64; kt++) {
    #pragma unroll
    for (int i = 0; i < 2; i++)
      __builtin_amdgcn_global_load_lds((const unsigned int*)(gK + (kt * 64 + 32 * i) * 64),
                                       (unsigned int*)(lK + 32 * i * 64), 16, 0, 0);
    #pragma unroll
    for (int i2 = 0; i2 < 2; i2++) {          // V: coalesced uint4 load, swizzled store
      int vec = t + i2 * 256;
      int kv = vec >> 3, c7 = vec & 7;
      uint4 val = *(const uint4*)(v + base + (kt * 64 + kv) * 64 + c7 * 8);
      unsigned short tmp[8];
      *(uint4*)tmp = val;
      #pragma unroll
      for (int i = 0; i < 8; i++)
        sVt[(c7 * 8 + i) * 64 + (kv ^ (c7 << 3))] = tmp[i];
    }
    __syncthreads();

    f32x4 s_acc[4];
    #pragma unroll
    for (int nt = 0; nt < 4; nt++) {
      bf16x8 kb0 = *(const bf16x8*)(&sK[(nt * 16 + l16) * 64 + quad * 8]);
      bf16x8 kb1 = *(const bf16x8*)(&sK[(nt * 16 + l16) * 64 + 32 + quad * 8]);
      f32x4 a = (f32x4){0.f, 0.f, 0.f, 0.f};
      a = __builtin_amdgcn_mfma_f32_16x16x32_bf16(qa[0], kb0, a, 0, 0, 0);
      a = __builtin_amdgcn_mfma_f32_16x16x32_bf16(qa[1], kb1, a, 0, 0, 0);
      s_acc[nt] = a;
    }
    #pragma unroll
    for (int r = 0; r < 4; r++) {
      float mx = -1e30f;
      #pragma unroll
      for (int nt = 0; nt < 4; nt++) mx = fmaxf(mx, s_acc[nt][r]);
      #pragma unroll
      for (int off = 1; off < 16; off <<= 1) mx = fmaxf(mx, __shfl_xor(mx, off));
      float mnew = fmaxf(m_i[r], mx);
      float alpha = __expf(m_i[r] - mnew);
      float rsum = 0.f;
      #pragma unroll
      for (int nt = 0; nt < 4; nt++) {
        float p = __expf(s_acc[nt][r] - mnew);
        s_acc[nt][r] = p;
        rsum += p;
      }
      #pragma unroll
      for (int off = 1; off < 16; off <<= 1) rsum += __shfl_xor(rsum, off);
      l_i[r] = l_i[r] * alpha + rsum;
      m_i[r] = mnew;
      #pragma unroll
      for (int dt = 0; dt < 4; dt++) o_acc[dt][r] *= alpha;
    }
    // P: C-layout -> A-layout via per-wave LDS region
    #pragma unroll
    for (int nt = 0; nt < 4; nt++)
      #pragma unroll
      for (int r = 0; r < 4; r++)
        sP[wave][quad * 4 + r][nt * 16 + l16] = f2bf(s_acc[nt][r]);
    __asm__ volatile("s_waitcnt lgkmcnt(0)" ::: "memory");
    bf16x8 pa0 = *(const bf16x8*)(&sP[wave][l16][quad * 8]);
    bf16x8 pa1 = *(const bf16x8*)(&sP[wave][l16][32 + quad * 8]);
    #pragma unroll
    for (int dt = 0; dt < 4; dt++) {
      int d0 = dt * 16 + l16;
      int m3 = (d0 >> 3) & 7;
      bf16x8 vb0 = *(const bf16x8*)(&sVt[d0 * 64 + ((quad ^ m3) << 3)]);
      bf16x8 vb1 = *(const bf16x8*)(&sVt[d0 * 64 + (((quad + 4) ^ m3) << 3)]);
      o_acc[dt] = __builtin_amdgcn_mfma_f32_16x16x32_bf16(pa0, vb0, o_acc[dt], 0, 0, 0);
      o_acc[dt] = __builtin_amdgcn_mfma_f32_16x16x32_bf16(pa1, vb1, o_acc[dt], 0, 0, 0);
    }
    __syncthreads();
  }

  const int b = bh >> 4, h = bh & 15;
  #pragma unroll
  for (int dt = 0; dt < 4; dt++)
    #pragma unroll
    for (int r = 0; r < 4; r++) {
      int n = qb * 64 + wave * 16 + quad * 4 + r;
      int tok = b * N_ + n;
      int col = h * 64 + dt * 16 + l16;
      o[tok * C_ + col] = f2bf(o_acc[dt][r] / l_i[r]);
    }
}

// ---------------- launcher ---------------------------------------------------
extern "C" void kernel_launch(void* const* d_in, const int* in_sizes, int n_in,
                              void* d_out, int out_size, void* d_ws, size_t ws_size,
                              hipStream_t stream) {
  const float* x   = (const float*)d_in[0];
  const float* rc  = (const float*)d_in[1];
  const float* rs  = (const float*)d_in[2];
  const float* g1  = (const float*)d_in[3];
  const float* be1 = (const float*)d_in[4];
  const float* Wq  = (const float*)d_in[5];
  const float* bq  = (const float*)d_in[6];
  const float* Wk  = (const float*)d_in[7];
  const float* bk  = (const float*)d_in[8];
  const float* Wv  = (const float*)d_in[9];
  const float* bv  = (const float*)d_in[10];
  const float* Wo  = (const float*)d_in[11];
  const float* bo  = (const float*)d_in[12];
  const float* g2  = (const float*)d_in[13];
  const float* be2 = (const float*)d_in[14];
  const float* W1  = (const float*)d_in[15];
  const float* b1m = (const float*)d_in[16];
  const float* W2  = (const float*)d_in[17];
  const float* b2m = (const float*)d_in[18];
  float* out = (float*)d_out;

  char* ws = (char*)d_ws;
  unsigned short* wqkv = (unsigned short*)(ws + 0);          // 3C*C bf16 (6 MB)
  unsigned short* wo   = (unsigned short*)(ws + 6291456);    // C*C  (2 MB)
  unsigned short* w1   = (unsigned short*)(ws + 8388608);    // F*C  (8 MB)
  unsigned short* w2   = (unsigned short*)(ws + 16777216);   // C*F  (8 MB)
  unsigned short* h1   = (unsigned short*)(ws + 25165824);   // M*C  (8 MB), reused as h2
  unsigned short* qkv  = (unsigned short*)(ws + 33554432);   // M*3C (24 MB)
  unsigned short* qa   = (unsigned short*)(ws + 58720256);   // 8 MB
  unsigned short* ka   = (unsigned short*)(ws + 67108864);   // 8 MB
  unsigned short* va   = (unsigned short*)(ws + 75497472);   // 8 MB
  unsigned short* ao   = (unsigned short*)(ws + 83886080);   // 8 MB
  float*          x1   = (float*)(ws + 92274688);            // 16 MB
  unsigned short* u    = (unsigned short*)(ws + 33554432);   // 32 MB, reuses qkv+qa (dead)
  unsigned short* h2   = h1;

  cvt_all<<<12288, 256, 0, stream>>>(
      (const float4*)Wq, (const float4*)Wk, (const float4*)Wv, (const float4*)Wo,
      (const float4*)W1, (const float4*)W2,
      (ushort4*)wqkv, (ushort4*)(wqkv + 1048576), (ushort4*)(wqkv + 2097152),
      (ushort4*)wo, (ushort4*)w1, (ushort4*)w2);

  ln_kernel<<<4096, 256, 0, stream>>>(x, g1, be1, h1);
  gemm_bt<0><<<dim3(24, 32), 256, 0, stream>>>(h1, wqkv, 1024, 3072, nullptr, nullptr, qkv, nullptr);
  rope_split<<<16384, 256, 0, stream>>>(qkv, bq, bk, bv, rc, rs, qa, ka, va);
  flash_attn<<<dim3(32, 32), 256, 0, stream>>>(qa, ka, va, ao);
  gemm_bt<1><<<dim3(8, 32), 256, 0, stream>>>(ao, wo, 1024, 1024, bo, x, nullptr, x1);
  ln_kernel<<<4096, 256, 0, stream>>>(x1, g2, be2, h2);
  gemm_bt<2><<<dim3(32, 32), 256, 0, stream>>>(h2, w1, 1024, 4096, b1m, nullptr, u, nullptr);
  gemm_bt<3><<<dim3(8, 32), 256, 0, stream>>>(u, w2, 4096, 1024, b2m, x1, nullptr, out);
}

// Round 3
// 463.405 us; speedup vs baseline: 1.1631x; 1.1631x over previous
//
#include <hip/hip_runtime.h>
#include <hip/hip_bf16.h>

#define B_ 2
#define N_ 2048
#define C_ 1024
#define H_ 16
#define D_ 64
#define F_ 4096
#define M_ 4096  // B_*N_

typedef __attribute__((ext_vector_type(8))) short bf16x8;
typedef __attribute__((ext_vector_type(4))) float f32x4;

__device__ inline unsigned short f2bf(float f) {
  unsigned int u = __float_as_uint(f);
  u = (u + 0x7FFFu + ((u >> 16) & 1u)) >> 16;
  return (unsigned short)u;
}
__device__ inline float bf2f(unsigned short s) {
  return __uint_as_float(((unsigned int)s) << 16);
}

// ---------------- all-weights fp32 -> bf16 in one launch ---------------------
__global__ __launch_bounds__(256)
void cvt_all(const float4* __restrict__ s0, const float4* __restrict__ s1,
             const float4* __restrict__ s2, const float4* __restrict__ s3,
             const float4* __restrict__ s4, const float4* __restrict__ s5,
             ushort4* __restrict__ d0, ushort4* __restrict__ d1,
             ushort4* __restrict__ d2, ushort4* __restrict__ d3,
             ushort4* __restrict__ d4, ushort4* __restrict__ d5) {
  int b = blockIdx.x;
  const float4* s; ushort4* d; int i;
  if      (b < 1024) { s = s0; d = d0; i = b * 256 + threadIdx.x; }
  else if (b < 2048) { s = s1; d = d1; i = (b - 1024) * 256 + threadIdx.x; }
  else if (b < 3072) { s = s2; d = d2; i = (b - 2048) * 256 + threadIdx.x; }
  else if (b < 4096) { s = s3; d = d3; i = (b - 3072) * 256 + threadIdx.x; }
  else if (b < 8192) { s = s4; d = d4; i = (b - 4096) * 256 + threadIdx.x; }
  else               { s = s5; d = d5; i = (b - 8192) * 256 + threadIdx.x; }
  float4 f = s[i];
  ushort4 o;
  o.x = f2bf(f.x); o.y = f2bf(f.y); o.z = f2bf(f.z); o.w = f2bf(f.w);
  d[i] = o;
}

// ---------------- LayerNorm: fp32 in -> bf16 out, one block per row (C=1024) --
__global__ __launch_bounds__(256)
void ln_kernel(const float* __restrict__ x, const float* __restrict__ g,
               const float* __restrict__ b, unsigned short* __restrict__ out) {
  __shared__ float red[8];
  const int row = blockIdx.x;
  const int t = threadIdx.x;
  const float4 xv = *(const float4*)(x + row * 1024 + t * 4);
  float s  = xv.x + xv.y + xv.z + xv.w;
  float sq = xv.x * xv.x + xv.y * xv.y + xv.z * xv.z + xv.w * xv.w;
  #pragma unroll
  for (int off = 32; off >= 1; off >>= 1) {
    s  += __shfl_down(s, off);
    sq += __shfl_down(sq, off);
  }
  const int lane = t & 63, wave = t >> 6;
  if (lane == 0) { red[wave * 2] = s; red[wave * 2 + 1] = sq; }
  __syncthreads();
  float ts = red[0] + red[2] + red[4] + red[6];
  float tq = red[1] + red[3] + red[5] + red[7];
  float mean = ts * (1.0f / 1024.0f);
  float var  = tq * (1.0f / 1024.0f) - mean * mean;
  float rstd = rsqrtf(var + 1e-6f);
  float xs[4] = {xv.x, xv.y, xv.z, xv.w};
  #pragma unroll
  for (int i = 0; i < 4; i++) {
    int c = t * 4 + i;
    float y = (xs[i] - mean) * rstd * g[c] + b[c];
    out[row * 1024 + c] = f2bf(y);
  }
}

// ---------------- GEMM: out[m,n] = sum_k A[m,k]*Bw[n,k] (+epilogue) ----------
// m97 structure: unpadded 128x64 LDS tiles + global_load_lds width=16.
template<int MODE>
__global__ __launch_bounds__(256)
void gemm_bt(const unsigned short* __restrict__ A,
             const unsigned short* __restrict__ Bw,
             int K, int Nout,
             const float* __restrict__ bias,
             const float* __restrict__ resid,
             unsigned short* __restrict__ out_bf,
             float* __restrict__ out_f32) {
  __shared__ unsigned short sA[128 * 64];
  __shared__ unsigned short sB[128 * 64];
  const int t = threadIdx.x;
  const int wave = t >> 6, lane = t & 63;
  const int quad = lane >> 4, l16 = lane & 15;
  const int wm = (wave & 1) * 64, wn = (wave >> 1) * 64;
  const int m0 = blockIdx.y * 128, n0 = blockIdx.x * 128;

  f32x4 acc[4][4];
  #pragma unroll
  for (int i = 0; i < 4; i++)
    #pragma unroll
    for (int j = 0; j < 4; j++) acc[i][j] = (f32x4){0.f, 0.f, 0.f, 0.f};

  const unsigned short* gA = A  + (m0 + (t >> 3)) * K + (t & 7) * 8;
  const unsigned short* gB = Bw + (n0 + (t >> 3)) * K + (t & 7) * 8;
  unsigned short* lA = &sA[(wave * 8) * 64];
  unsigned short* lB = &sB[(wave * 8) * 64];

  for (int k0 = 0; k0 < K; k0 += 64) {
    #pragma unroll
    for (int i = 0; i < 4; i++) {
      __builtin_amdgcn_global_load_lds((const unsigned int*)(gA + (32 * i) * K + k0),
                                       (unsigned int*)(lA + 32 * i * 64), 16, 0, 0);
      __builtin_amdgcn_global_load_lds((const unsigned int*)(gB + (32 * i) * K + k0),
                                       (unsigned int*)(lB + 32 * i * 64), 16, 0, 0);
    }
    __syncthreads();
    #pragma unroll
    for (int kk = 0; kk < 2; kk++) {
      bf16x8 af[4], bfr[4];
      #pragma unroll
      for (int i = 0; i < 4; i++)
        af[i] = *(const bf16x8*)(&sA[(wm + i * 16 + l16) * 64 + kk * 32 + quad * 8]);
      #pragma unroll
      for (int j = 0; j < 4; j++)
        bfr[j] = *(const bf16x8*)(&sB[(wn + j * 16 + l16) * 64 + kk * 32 + quad * 8]);
      #pragma unroll
      for (int i = 0; i < 4; i++)
        #pragma unroll
        for (int j = 0; j < 4; j++)
          acc[i][j] = __builtin_amdgcn_mfma_f32_16x16x32_bf16(af[i], bfr[j], acc[i][j], 0, 0, 0);
    }
    __syncthreads();
  }

  #pragma unroll
  for (int i = 0; i < 4; i++) {
    #pragma unroll
    for (int j = 0; j < 4; j++) {
      int col = n0 + wn + j * 16 + l16;
      #pragma unroll
      for (int r = 0; r < 4; r++) {
        int row = m0 + wm + i * 16 + quad * 4 + r;
        float v = acc[i][j][r];
        if (MODE == 0) {
          out_bf[row * Nout + col] = f2bf(v);
        } else if (MODE == 1) {
          out_f32[row * Nout + col] = v + bias[col] + resid[row * Nout + col];
        } else if (MODE == 2) {
          v += bias[col];
          float gl = 0.5f * v * (1.0f + erff(v * 0.70710678118654752f));
          out_bf[row * Nout + col] = f2bf(gl);
        } else {
          out_f32[row * Nout + col] = v + bias[col] + resid[row * Nout + col];
        }
      }
    }
  }
}

// ---------------- RoPE + bias + head split ----------------------------------
__global__ __launch_bounds__(256)
void rope_split(const unsigned short* __restrict__ qkv,
                const float* __restrict__ bq, const float* __restrict__ bk,
                const float* __restrict__ bv,
                const float* __restrict__ rc, const float* __restrict__ rs,
                unsigned short* __restrict__ qo, unsigned short* __restrict__ ko,
                unsigned short* __restrict__ vo) {
  int idx = blockIdx.x * 256 + threadIdx.x;
  int m = idx >> 10, c = idx & 1023;
  int h = c >> 6, d = c & 63;
  int b = m >> 11, n = m & 2047;
  int base = m * 3072;
  float qv = bf2f(qkv[base + c])        + bq[c];
  float kv = bf2f(qkv[base + 1024 + c]) + bk[c];
  float vv = bf2f(qkv[base + 2048 + c]) + bv[c];
  int c2 = (d < 32) ? c + 32 : c - 32;
  float qp = bf2f(qkv[base + c2])        + bq[c2];
  float kp = bf2f(qkv[base + 1024 + c2]) + bk[c2];
  float rqv = (d < 32) ? -qp : qp;
  float rkv = (d < 32) ? -kp : kp;
  float cs = rc[n * 64 + d], sn = rs[n * 64 + d];
  int oi = ((b * 16 + h) * 2048 + n) * 64 + d;
  qo[oi] = f2bf((qv * cs + rqv * sn) * 0.125f);   // fold D^-0.5
  ko[oi] = f2bf(kv * cs + rkv * sn);
  vo[oi] = f2bf(vv);
}

// ---------------- Flash attention, S^T/O^T orientation -----------------------
// S^T = mfma(K-frag, Q-frag): softmax dim (kv) lands in-register (16/lane) +
// 2 cross-quad shuffles; per-lane (q=l16) m/l/alpha state.
// O^T = mfma(V^T-frag, P^T-frag): alpha rescale + final 1/l fully in-lane.
// All LDS ops proved conflict-free: sK stride-72 (write/read (row+chunk)%8
// uniform), sVt XOR key (d>>3)^(d&7) (2-way writes, min-phase b128 reads),
// sPt stride-72 (b64 writes 4/bank uniform, b128 reads (l16+quad)%8 uniform).
__global__ __launch_bounds__(256)
void flash_attn(const unsigned short* __restrict__ q,
                const unsigned short* __restrict__ k,
                const unsigned short* __restrict__ v,
                unsigned short* __restrict__ o) {
  __shared__ unsigned short sK[64 * 72];
  __shared__ unsigned short sVt[64 * 64];
  __shared__ unsigned short sPt[4][16][72];
  const int t = threadIdx.x;
  const int wave = t >> 6, lane = t & 63;
  const int quad = lane >> 4, l16 = lane & 15;
  const int bh = blockIdx.y;
  const int qb = blockIdx.x;
  const int base = bh * (N_ * D_);

  // Q as B-operand: lane l16 = q-col, regs = k-dim
  bf16x8 qa[2];
  {
    int qrow = qb * 64 + wave * 16 + l16;
    #pragma unroll
    for (int kk = 0; kk < 2; kk++)
      qa[kk] = *(const bf16x8*)(q + base + qrow * D_ + kk * 32 + quad * 8);
  }
  float m_i = -1e30f, l_i = 0.f;   // per-lane: this lane's q = l16
  f32x4 o_acc[4];                  // O^T: col=q=l16, row d = dt*16+quad*4+r
  #pragma unroll
  for (int dt = 0; dt < 4; dt++) o_acc[dt] = (f32x4){0.f, 0.f, 0.f, 0.f};

  const int krow = t >> 3, kchunk = (t & 7) * 8;

  for (int kt = 0; kt < N_ / 64; kt++) {
    // K tile -> padded LDS (conflict-free b128 write)
    #pragma unroll
    for (int i = 0; i < 2; i++) {
      uint4 kval = *(const uint4*)(k + base + (kt * 64 + krow + 32 * i) * 64 + kchunk);
      *(uint4*)(&sK[(krow + 32 * i) * 72 + kchunk]) = kval;
    }
    // V tile -> transposed+swizzled LDS (2-way scalar writes = free)
    #pragma unroll
    for (int i2 = 0; i2 < 2; i2++) {
      int vec = t + i2 * 256;
      int kv = vec >> 3, c7 = vec & 7;
      uint4 val = *(const uint4*)(v + base + (kt * 64 + kv) * 64 + c7 * 8);
      unsigned short tmp[8];
      *(uint4*)tmp = val;
      #pragma unroll
      for (int i = 0; i < 8; i++) {
        int key = (c7 ^ i) & 7;              // = ((d>>3) ^ (d&7)) for d=c7*8+i
        sVt[(c7 * 8 + i) * 64 + (kv ^ (key << 3))] = tmp[i];
      }
    }
    __syncthreads();

    // S^T tiles: rows kv = nt*16+quad*4+r, cols q = l16
    f32x4 s_acc[4];
    #pragma unroll
    for (int nt = 0; nt < 4; nt++) {
      bf16x8 kb0 = *(const bf16x8*)(&sK[(nt * 16 + l16) * 72 + quad * 8]);
      bf16x8 kb1 = *(const bf16x8*)(&sK[(nt * 16 + l16) * 72 + 32 + quad * 8]);
      f32x4 a = (f32x4){0.f, 0.f, 0.f, 0.f};
      a = __builtin_amdgcn_mfma_f32_16x16x32_bf16(kb0, qa[0], a, 0, 0, 0);
      a = __builtin_amdgcn_mfma_f32_16x16x32_bf16(kb1, qa[1], a, 0, 0, 0);
      s_acc[nt] = a;
    }
    // online softmax: in-lane over 16, then cross-quad (2 shuffles each)
    float mx = -1e30f;
    #pragma unroll
    for (int nt = 0; nt < 4; nt++)
      #pragma unroll
      for (int r = 0; r < 4; r++) mx = fmaxf(mx, s_acc[nt][r]);
    mx = fmaxf(mx, __shfl_xor(mx, 16));
    mx = fmaxf(mx, __shfl_xor(mx, 32));
    float mnew = fmaxf(m_i, mx);
    float alpha = __expf(m_i - mnew);
    float rsum = 0.f;
    #pragma unroll
    for (int nt = 0; nt < 4; nt++)
      #pragma unroll
      for (int r = 0; r < 4; r++) {
        float p = __expf(s_acc[nt][r] - mnew);
        s_acc[nt][r] = p;
        rsum += p;
      }
    rsum += __shfl_xor(rsum, 16);
    rsum += __shfl_xor(rsum, 32);
    l_i = l_i * alpha + rsum;
    m_i = mnew;
    #pragma unroll
    for (int dt = 0; dt < 4; dt++)
      #pragma unroll
      for (int r = 0; r < 4; r++) o_acc[dt][r] *= alpha;

    // P^T -> LDS: packed b64 (4 bf16, r=0..3) per nt
    #pragma unroll
    for (int nt = 0; nt < 4; nt++) {
      ushort4 pk;
      pk.x = f2bf(s_acc[nt][0]); pk.y = f2bf(s_acc[nt][1]);
      pk.z = f2bf(s_acc[nt][2]); pk.w = f2bf(s_acc[nt][3]);
      *(ushort4*)(&sPt[wave][l16][nt * 16 + quad * 4]) = pk;
    }
    __asm__ volatile("s_waitcnt lgkmcnt(0)" ::: "memory");
    // P^T as B-operand: lane l16 = q, regs kv
    bf16x8 pt0 = *(const bf16x8*)(&sPt[wave][l16][quad * 8]);
    bf16x8 pt1 = *(const bf16x8*)(&sPt[wave][l16][32 + quad * 8]);
    // V^T as A-operand: lane l16 -> d = dt*16+l16, regs kv (swizzled read)
    #pragma unroll
    for (int dt = 0; dt < 4; dt++) {
      int d0 = dt * 16 + l16;
      int key = ((d0 >> 3) ^ (d0 & 7)) & 7;
      bf16x8 va0 = *(const bf16x8*)(&sVt[d0 * 64 + ((quad ^ key) << 3)]);
      bf16x8 va1 = *(const bf16x8*)(&sVt[d0 * 64 + (((quad + 4) ^ key) << 3)]);
      o_acc[dt] = __builtin_amdgcn_mfma_f32_16x16x32_bf16(va0, pt0, o_acc[dt], 0, 0, 0);
      o_acc[dt] = __builtin_amdgcn_mfma_f32_16x16x32_bf16(va1, pt1, o_acc[dt], 0, 0, 0);
    }
    __syncthreads();
  }

  // O^T epilogue: q = l16 (in-lane 1/l), d = dt*16 + quad*4 + r
  const int b = bh >> 4, h = bh & 15;
  const float inv = 1.0f / l_i;
  const int tok = b * N_ + qb * 64 + wave * 16 + l16;
  #pragma unroll
  for (int dt = 0; dt < 4; dt++)
    #pragma unroll
    for (int r = 0; r < 4; r++) {
      int col = h * 64 + dt * 16 + quad * 4 + r;
      o[tok * C_ + col] = f2bf(o_acc[dt][r] * inv);
    }
}

// ---------------- launcher ---------------------------------------------------
extern "C" void kernel_launch(void* const* d_in, const int* in_sizes, int n_in,
                              void* d_out, int out_size, void* d_ws, size_t ws_size,
                              hipStream_t stream) {
  const float* x   = (const float*)d_in[0];
  const float* rc  = (const float*)d_in[1];
  const float* rs  = (const float*)d_in[2];
  const float* g1  = (const float*)d_in[3];
  const float* be1 = (const float*)d_in[4];
  const float* Wq  = (const float*)d_in[5];
  const float* bq  = (const float*)d_in[6];
  const float* Wk  = (const float*)d_in[7];
  const float* bk  = (const float*)d_in[8];
  const float* Wv  = (const float*)d_in[9];
  const float* bv  = (const float*)d_in[10];
  const float* Wo  = (const float*)d_in[11];
  const float* bo  = (const float*)d_in[12];
  const float* g2  = (const float*)d_in[13];
  const float* be2 = (const float*)d_in[14];
  const float* W1  = (const float*)d_in[15];
  const float* b1m = (const float*)d_in[16];
  const float* W2  = (const float*)d_in[17];
  const float* b2m = (const float*)d_in[18];
  float* out = (float*)d_out;

  char* ws = (char*)d_ws;
  unsigned short* wqkv = (unsigned short*)(ws + 0);          // 6 MB
  unsigned short* wo   = (unsigned short*)(ws + 6291456);    // 2 MB
  unsigned short* w1   = (unsigned short*)(ws + 8388608);    // 8 MB
  unsigned short* w2   = (unsigned short*)(ws + 16777216);   // 8 MB
  unsigned short* h1   = (unsigned short*)(ws + 25165824);   // 8 MB (reused as h2)
  unsigned short* qkv  = (unsigned short*)(ws + 33554432);   // 24 MB
  unsigned short* qa   = (unsigned short*)(ws + 58720256);   // 8 MB
  unsigned short* ka   = (unsigned short*)(ws + 67108864);   // 8 MB
  unsigned short* va   = (unsigned short*)(ws + 75497472);   // 8 MB
  unsigned short* ao   = (unsigned short*)(ws + 83886080);   // 8 MB
  float*          x1   = (float*)(ws + 92274688);            // 16 MB
  unsigned short* u    = (unsigned short*)(ws + 33554432);   // reuses qkv+qa (dead)
  unsigned short* h2   = h1;

  cvt_all<<<12288, 256, 0, stream>>>(
      (const float4*)Wq, (const float4*)Wk, (const float4*)Wv, (const float4*)Wo,
      (const float4*)W1, (const float4*)W2,
      (ushort4*)wqkv, (ushort4*)(wqkv + 1048576), (ushort4*)(wqkv + 2097152),
      (ushort4*)wo, (ushort4*)w1, (ushort4*)w2);

  ln_kernel<<<4096, 256, 0, stream>>>(x, g1, be1, h1);
  gemm_bt<0><<<dim3(24, 32), 256, 0, stream>>>(h1, wqkv, 1024, 3072, nullptr, nullptr, qkv, nullptr);
  rope_split<<<16384, 256, 0, stream>>>(qkv, bq, bk, bv, rc, rs, qa, ka, va);
  flash_attn<<<dim3(32, 32), 256, 0, stream>>>(qa, ka, va, ao);
  gemm_bt<1><<<dim3(8, 32), 256, 0, stream>>>(ao, wo, 1024, 1024, bo, x, nullptr, x1);
  ln_kernel<<<4096, 256, 0, stream>>>(x1, g2, be2, h2);
  gemm_bt<2><<<dim3(32, 32), 256, 0, stream>>>(h2, w1, 1024, 4096, b1m, nullptr, u, nullptr);
  gemm_bt<3><<<dim3(8, 32), 256, 0, stream>>>(u, w2, 4096, 1024, b2m, x1, nullptr, out);
}